// Round 14
// baseline (696.132 us; speedup 1.0000x reference)
//
#include <hip/hip_runtime.h>
#include <math.h>

#define Bn 64
#define Tn 128
#define TCn 512
#define CEn 64
#define CHn 256
#define TAGSn 50
#define DWPn 640   // word-LSTM input dim padded 612 -> 640

typedef float f32x4 __attribute__((ext_vector_type(4)));
typedef int   i32x4 __attribute__((ext_vector_type(4)));
typedef short bf16x8 __attribute__((ext_vector_type(8)));

#define DEQ 3.07578740157480315e-5f   // 1/(256*127)

__device__ __forceinline__ float sigf(float x){ return 1.0f/(1.0f+expf(-x)); }

__device__ __forceinline__ float fsig(float x){
  return __builtin_amdgcn_rcpf(1.f + exp2f(-1.4426950408889634f*x));
}
__device__ __forceinline__ float ftanh(float x){
  return 1.f - 2.f*__builtin_amdgcn_rcpf(1.f + exp2f(2.885390081777927f*x));
}

// barrier that drains only LDS (keeps global loads/stores in flight)
__device__ __forceinline__ void bar_lds(){
  asm volatile("s_waitcnt lgkmcnt(0)\n\ts_barrier" ::: "memory");
}

// f32 <-> bf16 (RNE)
__device__ __forceinline__ unsigned short f2bf(float x){
  unsigned u = __float_as_uint(x);
  u += 0x7fffu + ((u>>16)&1u);
  return (unsigned short)(u>>16);
}
__device__ __forceinline__ float bf2f(unsigned short h){
  return __uint_as_float(((unsigned)h)<<16);
}

// ---------------------------------------------------------------------------
// CW[d][c][u*4+k] = b_d[k*256+u] + sum_e ceW[c][e]*Wih_d[k*256+u][e]
__global__ void k_prep_cw(const float* __restrict__ ceW,
                          const float* __restrict__ Wf, const float* __restrict__ bf,
                          const float* __restrict__ Wb, const float* __restrict__ bb,
                          float* __restrict__ CWf, float* __restrict__ CWb){
  const int c = blockIdx.x, u = threadIdx.x;
  const float* Wih  = blockIdx.y ? Wb : Wf;
  const float* bias = blockIdx.y ? bb : bf;
  float*       CW   = blockIdx.y ? CWb : CWf;
  __shared__ float ce[CEn];
  if (u < CEn) ce[u] = ceW[c*CEn + u];
  __syncthreads();
  float a[4];
  #pragma unroll
  for (int k=0;k<4;k++){
    const float* wr = Wih + (size_t)(k*CHn+u)*CEn;
    float s = bias[k*CHn+u];
    #pragma unroll 4
    for (int e=0;e<CEn;e++) s += ce[e]*wr[e];
    a[k]=s;
  }
  ((float4*)CW)[c*CHn+u] = make_float4(a[0],a[1],a[2],a[3]);
}

// i8 Whh, gate-tile row permutation:
//   out row rp = wv*64 + nt*16 + m  <-  src row nt*256 + wv*16 + m
__global__ void k_prep_w8(const float* __restrict__ W0, const float* __restrict__ W1,
                          const float* __restrict__ W2, const float* __restrict__ W3,
                          unsigned short* __restrict__ O0, unsigned short* __restrict__ O1,
                          unsigned short* __restrict__ O2, unsigned short* __restrict__ O3){
  const int w = blockIdx.y;
  const float* W = (w==0)?W0:(w==1)?W1:(w==2)?W2:W3;
  unsigned short* O = (w==0)?O0:(w==1)?O1:(w==2)?O2:O3;
  const int i = blockIdx.x*256 + threadIdx.x;      // 131072 pairs
  const int rp = i >> 7;
  const int kp = (i & 127) * 2;
  const int sr = (((rp>>4)&3)*256) + ((rp>>6)*16) + (rp&15);
  const int b0 = (int)rintf(fminf(fmaxf(W[(size_t)sr*CHn + kp  ]*256.f,-127.f),127.f));
  const int b1 = (int)rintf(fminf(fmaxf(W[(size_t)sr*CHn + kp+1]*256.f,-127.f),127.f));
  O[(size_t)rp*128 + (kp>>1)] = (unsigned short)((b0 & 0xff) | ((b1 & 0xff) << 8));
}

// pad word Wih (1024,612) -> bf16 (1024,640)
__global__ void k_pad16(const float* __restrict__ Wf, const float* __restrict__ Wb,
                        unsigned short* __restrict__ Pf, unsigned short* __restrict__ Pb){
  const int j = blockIdx.x;
  const float* Win        = blockIdx.y ? Wb : Wf;
  unsigned short* Wout    = blockIdx.y ? Pb : Pf;
  for (int col=threadIdx.x; col<DWPn; col+=256)
    Wout[(size_t)j*DWPn+col] = (col<612) ? f2bf(Win[(size_t)j*612+col]) : 0;
}

// hwWt/hwWg (512,512) -> bf16
__global__ void k_w16(const float* __restrict__ Wt, const float* __restrict__ Wg,
                      unsigned short* __restrict__ Ot, unsigned short* __restrict__ Og){
  const int j = blockIdx.x;
  const float* W       = blockIdx.y ? Wg : Wt;
  unsigned short* O    = blockIdx.y ? Og : Ot;
  for (int col=threadIdx.x; col<512; col+=256)
    O[(size_t)j*512+col] = f2bf(W[(size_t)j*512+col]);
}

// emW (50,512) -> bf16 (128,512) padded; emb -> fp32 (128) padded
__global__ void k_em16(const float* __restrict__ emW, const float* __restrict__ emb,
                       unsigned short* __restrict__ Wp, float* __restrict__ bp){
  const int j = blockIdx.x;
  for (int col=threadIdx.x; col<512; col+=256)
    Wp[(size_t)j*512+col] = (j<TAGSn) ? f2bf(emW[(size_t)j*512+col]) : 0;
  if (threadIdx.x==0) bp[j] = (j<TAGSn) ? emb[j] : 0.f;
}

// stable-compaction ranks from cmakers only; grid (64,2), 64 threads (1 wave)
__global__ void k_prep_pos(const float* __restrict__ cmf, const float* __restrict__ cmb,
                           int* __restrict__ pf, int* __restrict__ pb){
  const float* cm = blockIdx.y ? cmb : cmf;
  int* pos        = blockIdx.y ? pb : pf;
  const int n = blockIdx.x, lane = threadIdx.x;
  int base = 0;
  for (int c=0;c<TCn/64;c++){
    int t = c*64 + lane;
    bool m = cm[n*TCn+t] != 0.f;
    unsigned long long bal = __ballot(m);
    int before = __popcll(bal & ((1ULL<<lane)-1ULL));
    int r = base + before;
    pos[n*TCn+t] = (m && r < Tn) ? r : -1;
    base += __popcll(bal);
  }
}

// ---------------------------------------------------------------------------
// char LSTM via i8 MFMA, gates in-register, 1 barrier/step, unroll-2,
// precomputed LDS addrs, DPP pack, zero-row A-read skip.
// 32 blocks, 1024 threads = 16 waves.
__global__ __launch_bounds__(1024, 4)
void k_char_lstm(const int* __restrict__ cmf, const int* __restrict__ cmb,
                 const float* __restrict__ CWf, const float* __restrict__ CWb,
                 const unsigned char* __restrict__ W8f, const unsigned char* __restrict__ W8b,
                 const int* __restrict__ posf, const int* __restrict__ posb,
                 unsigned short* __restrict__ sub16){
  const int dir = blockIdx.x >> 4, mg = blockIdx.x & 15;
  const int n0 = mg*4;
  const int t1 = threadIdx.x;
  const int wv = t1 >> 6, lane = t1 & 63;
  const int m = lane & 15, g = lane >> 4;
  const int*    cm  = dir ? cmb : cmf;
  const float4* CW  = (const float4*)(dir ? CWb : CWf);
  const unsigned char* W8 = dir ? W8b : W8f;
  const int*    pos = dir ? posb : posf;
  const int dofs = dir ? CHn : 0;

  __shared__ unsigned hbw[2][16][64];   // i8 h, 16B chunk idx XOR row; rows 4j = seq j

  i32x4 Bfr[4][4];
  #pragma unroll
  for (int nt=0;nt<4;nt++)
    #pragma unroll
    for (int kt=0;kt<4;kt++)
      Bfr[nt][kt] = *(const i32x4*)(W8 + (size_t)(wv*64 + nt*16 + m)*256 + kt*64 + g*16);

  for (int j=t1; j<2*16*64; j+=1024) ((unsigned*)hbw)[j] = 0u;
  const int uu = wv*16 + m;
  const int seq = n0 + g;
  const bool ard = (m & 3) == 0;       // only these lanes hold nonzero A rows
  const int* cmp  = cm  + seq*TCn;
  const int* posp = pos + seq*TCn;
  unsigned short* subp = sub16 + (size_t)seq*Tn*512 + dofs + uu;

  // precomputed LDS addresses (two parity sets)
  const int dwi = ((wv ^ (4*g)) << 2) | (m >> 2);
  unsigned* wp0 = &hbw[1][4*g][dwi];   // body par=0 writes buf 1
  unsigned* wp1 = &hbw[0][4*g][dwi];
  const i32x4* rp0[4]; const i32x4* rp1[4];
  {
    const char* r0 = (const char*)&hbw[0][0][0] + m*256;
    const char* r1 = (const char*)&hbw[1][0][0] + m*256;
    #pragma unroll
    for (int kt=0;kt<4;kt++){
      const int off = ((kt*4+g)^m)<<4;
      rp0[kt] = (const i32x4*)(r0 + off);
      rp1[kt] = (const i32x4*)(r1 + off);
    }
  }
  float cst = 0.f;
  __syncthreads();

  int    pp = posp[0];
  float4 cw = CW[(size_t)cmp[0]*CHn + uu];

#define CBODY(T, RP, WP) { \
    i32x4 a0={0,0,0,0}, a1={0,0,0,0}, a2={0,0,0,0}, a3={0,0,0,0}; \
    if (ard){ a0 = *(RP)[0]; a1 = *(RP)[1]; a2 = *(RP)[2]; a3 = *(RP)[3]; } \
    const int tn_ = ((T)+1 < TCn) ? (T)+1 : (T); \
    const int ci2 = cmp[tn_]; \
    const int pp2 = posp[tn_]; \
    const float4 cw2 = CW[(size_t)ci2*CHn + uu]; \
    i32x4 c0={0,0,0,0}, c1={0,0,0,0}, c2={0,0,0,0}, c3={0,0,0,0}; \
    c0 = __builtin_amdgcn_mfma_i32_16x16x64_i8(a0, Bfr[0][0], c0, 0,0,0); \
    c1 = __builtin_amdgcn_mfma_i32_16x16x64_i8(a0, Bfr[1][0], c1, 0,0,0); \
    c2 = __builtin_amdgcn_mfma_i32_16x16x64_i8(a0, Bfr[2][0], c2, 0,0,0); \
    c3 = __builtin_amdgcn_mfma_i32_16x16x64_i8(a0, Bfr[3][0], c3, 0,0,0); \
    c0 = __builtin_amdgcn_mfma_i32_16x16x64_i8(a1, Bfr[0][1], c0, 0,0,0); \
    c1 = __builtin_amdgcn_mfma_i32_16x16x64_i8(a1, Bfr[1][1], c1, 0,0,0); \
    c2 = __builtin_amdgcn_mfma_i32_16x16x64_i8(a1, Bfr[2][1], c2, 0,0,0); \
    c3 = __builtin_amdgcn_mfma_i32_16x16x64_i8(a1, Bfr[3][1], c3, 0,0,0); \
    c0 = __builtin_amdgcn_mfma_i32_16x16x64_i8(a2, Bfr[0][2], c0, 0,0,0); \
    c1 = __builtin_amdgcn_mfma_i32_16x16x64_i8(a2, Bfr[1][2], c1, 0,0,0); \
    c2 = __builtin_amdgcn_mfma_i32_16x16x64_i8(a2, Bfr[2][2], c2, 0,0,0); \
    c3 = __builtin_amdgcn_mfma_i32_16x16x64_i8(a2, Bfr[3][2], c3, 0,0,0); \
    c0 = __builtin_amdgcn_mfma_i32_16x16x64_i8(a3, Bfr[0][3], c0, 0,0,0); \
    c1 = __builtin_amdgcn_mfma_i32_16x16x64_i8(a3, Bfr[1][3], c1, 0,0,0); \
    c2 = __builtin_amdgcn_mfma_i32_16x16x64_i8(a3, Bfr[2][3], c2, 0,0,0); \
    c3 = __builtin_amdgcn_mfma_i32_16x16x64_i8(a3, Bfr[3][3], c3, 0,0,0); \
    const float zi = fmaf((float)c0[0], DEQ, cw.x); \
    const float zf = fmaf((float)c1[0], DEQ, cw.y); \
    const float zg = fmaf((float)c2[0], DEQ, cw.z); \
    const float zo = fmaf((float)c3[0], DEQ, cw.w); \
    cst = fsig(zf)*cst + fsig(zi)*ftanh(zg); \
    const float hn = fsig(zo)*ftanh(cst); \
    int vv = ((int)rintf(hn*127.f)) & 0xff; \
    int tv = __builtin_amdgcn_mov_dpp(vv, 0xB1, 0xF, 0xF, true); \
    vv = (lane&1) ? ((vv<<8)|tv) : ((tv<<8)|vv); \
    tv = __builtin_amdgcn_mov_dpp(vv, 0x4E, 0xF, 0xF, true); \
    vv = (lane&2) ? ((vv<<16)|tv) : ((tv<<16)|vv); \
    if ((lane&3)==0) *(WP) = (unsigned)vv; \
    if (pp>=0) subp[(size_t)pp*512] = f2bf(hn); \
    bar_lds(); \
    pp = pp2; cw = cw2; }

  for (int t=0;t<TCn;t+=2){
    #pragma unroll
    for (int nt=0;nt<4;nt++)
      #pragma unroll
      for (int kt=0;kt<4;kt++)
        asm volatile("" : "+v"(Bfr[nt][kt]));
    CBODY(t,   rp0, wp0)
    CBODY(t+1, rp1, wp1)
  }
#undef CBODY
}

// ---------------------------------------------------------------------------
// word LSTM via i8 MFMA, same structure; writes bf16 hout. 64 blocks.
__global__ __launch_bounds__(1024, 4)
void k_word_lstm(const float* __restrict__ wXf, const float* __restrict__ wXb,
                 const unsigned char* __restrict__ W8f, const unsigned char* __restrict__ W8b,
                 unsigned short* __restrict__ hout16){
  const int dir = blockIdx.x >> 5, mg = blockIdx.x & 31;
  const int t0r = mg*4;
  const int t1 = threadIdx.x;
  const int wv = t1 >> 6, lane = t1 & 63;
  const int m = lane & 15, g = lane >> 4;
  const float* wX = dir ? wXb : wXf;
  const unsigned char* W8 = dir ? W8b : W8f;
  const int dofs = dir ? CHn : 0;

  __shared__ unsigned hbw[2][16][64];

  i32x4 Bfr[4][4];
  #pragma unroll
  for (int nt=0;nt<4;nt++)
    #pragma unroll
    for (int kt=0;kt<4;kt++)
      Bfr[nt][kt] = *(const i32x4*)(W8 + (size_t)(wv*64 + nt*16 + m)*256 + kt*64 + g*16);

  for (int j=t1; j<2*16*64; j+=1024) ((unsigned*)hbw)[j] = 0u;
  const int uu = wv*16 + m;
  const int row = t0r + g;
  const bool ard = (m & 3) == 0;
  const float* xbase = wX + (size_t)row*1024 + uu;
  unsigned short* hop = hout16 + (size_t)row*512 + dofs + uu;

  const int dwi = ((wv ^ (4*g)) << 2) | (m >> 2);
  unsigned* wp0 = &hbw[1][4*g][dwi];
  unsigned* wp1 = &hbw[0][4*g][dwi];
  const i32x4* rp0[4]; const i32x4* rp1[4];
  {
    const char* r0 = (const char*)&hbw[0][0][0] + m*256;
    const char* r1 = (const char*)&hbw[1][0][0] + m*256;
    #pragma unroll
    for (int kt=0;kt<4;kt++){
      const int off = ((kt*4+g)^m)<<4;
      rp0[kt] = (const i32x4*)(r0 + off);
      rp1[kt] = (const i32x4*)(r1 + off);
    }
  }
  float cst = 0.f;
  __syncthreads();

  {
    const int n00 = dir ? 63 : 0;
    const float* xp0 = xbase + (size_t)n00*131072;
    float4 zin = make_float4(xp0[0], xp0[256], xp0[512], xp0[768]);

#define WBODY(S, RP, WP) { \
    i32x4 a0={0,0,0,0}, a1={0,0,0,0}, a2={0,0,0,0}, a3={0,0,0,0}; \
    if (ard){ a0 = *(RP)[0]; a1 = *(RP)[1]; a2 = *(RP)[2]; a3 = *(RP)[3]; } \
    const int n = dir ? (63-(S)) : (S); \
    const int sn_ = ((S)+1 < 64) ? (S)+1 : (S); \
    const int n2 = dir ? (63-sn_) : sn_; \
    const float* xp2 = xbase + (size_t)n2*131072; \
    const float4 zin2 = make_float4(xp2[0], xp2[256], xp2[512], xp2[768]); \
    i32x4 c0={0,0,0,0}, c1={0,0,0,0}, c2={0,0,0,0}, c3={0,0,0,0}; \
    c0 = __builtin_amdgcn_mfma_i32_16x16x64_i8(a0, Bfr[0][0], c0, 0,0,0); \
    c1 = __builtin_amdgcn_mfma_i32_16x16x64_i8(a0, Bfr[1][0], c1, 0,0,0); \
    c2 = __builtin_amdgcn_mfma_i32_16x16x64_i8(a0, Bfr[2][0], c2, 0,0,0); \
    c3 = __builtin_amdgcn_mfma_i32_16x16x64_i8(a0, Bfr[3][0], c3, 0,0,0); \
    c0 = __builtin_amdgcn_mfma_i32_16x16x64_i8(a1, Bfr[0][1], c0, 0,0,0); \
    c1 = __builtin_amdgcn_mfma_i32_16x16x64_i8(a1, Bfr[1][1], c1, 0,0,0); \
    c2 = __builtin_amdgcn_mfma_i32_16x16x64_i8(a1, Bfr[2][1], c2, 0,0,0); \
    c3 = __builtin_amdgcn_mfma_i32_16x16x64_i8(a1, Bfr[3][1], c3, 0,0,0); \
    c0 = __builtin_amdgcn_mfma_i32_16x16x64_i8(a2, Bfr[0][2], c0, 0,0,0); \
    c1 = __builtin_amdgcn_mfma_i32_16x16x64_i8(a2, Bfr[1][2], c1, 0,0,0); \
    c2 = __builtin_amdgcn_mfma_i32_16x16x64_i8(a2, Bfr[2][2], c2, 0,0,0); \
    c3 = __builtin_amdgcn_mfma_i32_16x16x64_i8(a2, Bfr[3][2], c3, 0,0,0); \
    c0 = __builtin_amdgcn_mfma_i32_16x16x64_i8(a3, Bfr[0][3], c0, 0,0,0); \
    c1 = __builtin_amdgcn_mfma_i32_16x16x64_i8(a3, Bfr[1][3], c1, 0,0,0); \
    c2 = __builtin_amdgcn_mfma_i32_16x16x64_i8(a3, Bfr[2][3], c2, 0,0,0); \
    c3 = __builtin_amdgcn_mfma_i32_16x16x64_i8(a3, Bfr[3][3], c3, 0,0,0); \
    const float zi = fmaf((float)c0[0], DEQ, zin.x); \
    const float zf = fmaf((float)c1[0], DEQ, zin.y); \
    const float zg = fmaf((float)c2[0], DEQ, zin.z); \
    const float zo = fmaf((float)c3[0], DEQ, zin.w); \
    cst = fsig(zf)*cst + fsig(zi)*ftanh(zg); \
    const float hn = fsig(zo)*ftanh(cst); \
    int vv = ((int)rintf(hn*127.f)) & 0xff; \
    int tv = __builtin_amdgcn_mov_dpp(vv, 0xB1, 0xF, 0xF, true); \
    vv = (lane&1) ? ((vv<<8)|tv) : ((tv<<8)|vv); \
    tv = __builtin_amdgcn_mov_dpp(vv, 0x4E, 0xF, 0xF, true); \
    vv = (lane&2) ? ((vv<<16)|tv) : ((tv<<16)|vv); \
    if ((lane&3)==0) *(WP) = (unsigned)vv; \
    hop[(size_t)n*65536] = f2bf(hn); \
    bar_lds(); \
    zin = zin2; }

    for (int s=0;s<64;s+=2){
      #pragma unroll
      for (int nt=0;nt<4;nt++)
        #pragma unroll
        for (int kt=0;kt<4;kt++)
          asm volatile("" : "+v"(Bfr[nt][kt]));
      WBODY(s,   rp0, wp0)
      WBODY(s+1, rp1, wp1)
    }
#undef WBODY
  }
}

// ---------------------------------------------------------------------------
// bf16 MFMA GEMM with register-staged double-buffer:
// C[m][n] = bias[n] + sum_k A[m][k]*W[n][k]; 128x128 tile, 256 thr, BK=32.
__global__ __launch_bounds__(256)
void k_gemm16(const unsigned short* __restrict__ A, int lda, int K,
              const unsigned short* __restrict__ W0, const unsigned short* __restrict__ W1, int ldw,
              const float* __restrict__ b0, const float* __restrict__ b1,
              float* __restrict__ C0, float* __restrict__ C1, int ldc){
  const unsigned short* W = blockIdx.z ? W1 : W0;
  const float* bias       = blockIdx.z ? b1 : b0;
  float*       C          = blockIdx.z ? C1 : C0;
  const int m0 = blockIdx.x*128, n0 = blockIdx.y*128;
  const int tid = threadIdx.x;
  const int wid = tid >> 6, l = tid & 63;
  const int wr = wid >> 1, wc = wid & 1;
  const int lm = l & 15, lk = l >> 4;
  __shared__ unsigned short As[128][40];
  __shared__ unsigned short Bs[128][40];
  f32x4 acc[4][4];
  #pragma unroll
  for (int i=0;i<4;i++)
    #pragma unroll
    for (int j=0;j<4;j++){ acc[i][j][0]=0.f; acc[i][j][1]=0.f; acc[i][j][2]=0.f; acc[i][j][3]=0.f; }

  const int sr = tid >> 1, sh = (tid & 1) * 16;
  const unsigned short* Ap = A + (size_t)(m0+sr)*lda + sh;
  const unsigned short* Wp = W + (size_t)(n0+sr)*ldw + sh;
  uint4 ra0 = *(const uint4*)(Ap);
  uint4 ra1 = *(const uint4*)(Ap + 8);
  uint4 rb0 = *(const uint4*)(Wp);
  uint4 rb1 = *(const uint4*)(Wp + 8);

  for (int kc=0; kc<K; kc+=32){
    *(uint4*)&As[sr][sh]   = ra0;
    *(uint4*)&As[sr][sh+8] = ra1;
    *(uint4*)&Bs[sr][sh]   = rb0;
    *(uint4*)&Bs[sr][sh+8] = rb1;
    __syncthreads();
    if (kc + 32 < K){               // prefetch next chunk under the MFMAs
      ra0 = *(const uint4*)(Ap + kc + 32);
      ra1 = *(const uint4*)(Ap + kc + 40);
      rb0 = *(const uint4*)(Wp + kc + 32);
      rb1 = *(const uint4*)(Wp + kc + 40);
    }
    bf16x8 af[4], bfr[4];
    #pragma unroll
    for (int mt=0;mt<4;mt++) af[mt]  = *(const bf16x8*)&As[wr*64+mt*16+lm][lk*8];
    #pragma unroll
    for (int nt=0;nt<4;nt++) bfr[nt] = *(const bf16x8*)&Bs[wc*64+nt*16+lm][lk*8];
    #pragma unroll
    for (int mt=0;mt<4;mt++)
      #pragma unroll
      for (int nt=0;nt<4;nt++)
        acc[mt][nt] = __builtin_amdgcn_mfma_f32_16x16x32_bf16(af[mt], bfr[nt], acc[mt][nt], 0,0,0);
    __syncthreads();
  }
  #pragma unroll
  for (int nt=0;nt<4;nt++){
    const int col = n0 + wc*64 + nt*16 + lm;
    const float bv = bias[col];
    #pragma unroll
    for (int mt=0;mt<4;mt++){
      const int r0 = m0 + wr*64 + mt*16 + lk*4;
      #pragma unroll
      for (int rg=0;rg<4;rg++)
        C[(size_t)(r0+rg)*ldc + col] = acc[mt][nt][rg] + bv;
    }
  }
}

// ---------------------------------------------------------------------------
// fused highway: zt = sub@Wt^T+bt, zg = sub@Wg^T+bg computed together,
// epilogue writes sub16 = sig(zg)*relu(zt) + (1-sig(zg))*sub16.
// grid (64,4), 256 threads, K=512.
__global__ __launch_bounds__(256, 1)
void k_hwgemm(unsigned short* __restrict__ sub16,
              const unsigned short* __restrict__ Wt, const unsigned short* __restrict__ Wg,
              const float* __restrict__ bt, const float* __restrict__ bg){
  const int m0 = blockIdx.x*128, n0 = blockIdx.y*128;
  const int tid = threadIdx.x;
  const int wid = tid >> 6, l = tid & 63;
  const int wr = wid >> 1, wc = wid & 1;
  const int lm = l & 15, lk = l >> 4;
  __shared__ unsigned short As[128][40];
  __shared__ unsigned short Bt[128][40];
  __shared__ unsigned short Bg[128][40];
  f32x4 zt[4][4], zg[4][4];
  #pragma unroll
  for (int i=0;i<4;i++)
    #pragma unroll
    for (int j=0;j<4;j++){
      zt[i][j][0]=0.f; zt[i][j][1]=0.f; zt[i][j][2]=0.f; zt[i][j][3]=0.f;
      zg[i][j][0]=0.f; zg[i][j][1]=0.f; zg[i][j][2]=0.f; zg[i][j][3]=0.f;
    }

  const int sr = tid >> 1, sh = (tid & 1) * 16;
  const unsigned short* Ap = sub16 + (size_t)(m0+sr)*512 + sh;
  const unsigned short* Tp = Wt + (size_t)(n0+sr)*512 + sh;
  const unsigned short* Gp = Wg + (size_t)(n0+sr)*512 + sh;
  uint4 ra0 = *(const uint4*)(Ap);
  uint4 ra1 = *(const uint4*)(Ap + 8);
  uint4 rt0 = *(const uint4*)(Tp);
  uint4 rt1 = *(const uint4*)(Tp + 8);
  uint4 rg0 = *(const uint4*)(Gp);
  uint4 rg1 = *(const uint4*)(Gp + 8);

  for (int kc=0; kc<512; kc+=32){
    *(uint4*)&As[sr][sh]   = ra0;
    *(uint4*)&As[sr][sh+8] = ra1;
    *(uint4*)&Bt[sr][sh]   = rt0;
    *(uint4*)&Bt[sr][sh+8] = rt1;
    *(uint4*)&Bg[sr][sh]   = rg0;
    *(uint4*)&Bg[sr][sh+8] = rg1;
    __syncthreads();
    if (kc + 32 < 512){
      ra0 = *(const uint4*)(Ap + kc + 32);
      ra1 = *(const uint4*)(Ap + kc + 40);
      rt0 = *(const uint4*)(Tp + kc + 32);
      rt1 = *(const uint4*)(Tp + kc + 40);
      rg0 = *(const uint4*)(Gp + kc + 32);
      rg1 = *(const uint4*)(Gp + kc + 40);
    }
    bf16x8 af[4], bt_[4], bg_[4];
    #pragma unroll
    for (int mt=0;mt<4;mt++) af[mt]  = *(const bf16x8*)&As[wr*64+mt*16+lm][lk*8];
    #pragma unroll
    for (int nt=0;nt<4;nt++){
      bt_[nt] = *(const bf16x8*)&Bt[wc*64+nt*16+lm][lk*8];
      bg_[nt] = *(const bf16x8*)&Bg[wc*64+nt*16+lm][lk*8];
    }
    #pragma unroll
    for (int mt=0;mt<4;mt++)
      #pragma unroll
      for (int nt=0;nt<4;nt++){
        zt[mt][nt] = __builtin_amdgcn_mfma_f32_16x16x32_bf16(af[mt], bt_[nt], zt[mt][nt], 0,0,0);
        zg[mt][nt] = __builtin_amdgcn_mfma_f32_16x16x32_bf16(af[mt], bg_[nt], zg[mt][nt], 0,0,0);
      }
    __syncthreads();
  }
  #pragma unroll
  for (int nt=0;nt<4;nt++){
    const int col = n0 + wc*64 + nt*16 + lm;
    const float btv = bt[col], bgv = bg[col];
    #pragma unroll
    for (int mt=0;mt<4;mt++){
      const int r0 = m0 + wr*64 + mt*16 + lk*4;
      #pragma unroll
      for (int rg=0;rg<4;rg++){
        const int row = r0 + rg;
        unsigned short* sp = sub16 + (size_t)row*512 + col;
        const float zt_v = zt[mt][nt][rg] + btv;
        const float zg_v = zg[mt][nt][rg] + bgv;
        const float gg = sigf(zg_v);
        const float tr = fmaxf(zt_v, 0.f);
        *sp = f2bf(gg*tr + (1.f-gg)*bf2f(*sp));
      }
    }
  }
}

// assemble padded word input (bf16)
__global__ void k_wasm16(const int* __restrict__ wmap, const float* __restrict__ weW,
                         const unsigned short* __restrict__ sub16,
                         unsigned short* __restrict__ wq16){
  const int m = blockIdx.x;
  const int wi = wmap[m];
  for (int col=threadIdx.x; col<DWPn; col+=256){
    unsigned short v = 0;
    if (col < 100)      v = f2bf(weW[(size_t)wi*100 + col]);
    else if (col < 612) v = sub16[(size_t)m*512 + (col-100)];
    wq16[(size_t)m*DWPn + col] = v;
  }
}

// crf[m][a][b] = em[m][b] + trans[a][b] ; em ld=128 ; float4 writes
__global__ __launch_bounds__(256)
void k_crf(const float* __restrict__ em, const float* __restrict__ trans,
           float* __restrict__ out){
  const int m = blockIdx.x;
  __shared__ float er[TAGSn];
  if (threadIdx.x < TAGSn) er[threadIdx.x] = em[(size_t)m*128 + threadIdx.x];
  __syncthreads();
  float4* o4 = (float4*)(out + (size_t)m*2500);
  const float4* t4 = (const float4*)trans;
  for (int r4=threadIdx.x; r4<625; r4+=256){
    const float4 tv = t4[r4];
    const int r = r4*4;
    float4 ov;
    ov.x = er[(r  ) % TAGSn] + tv.x;
    ov.y = er[(r+1) % TAGSn] + tv.y;
    ov.z = er[(r+2) % TAGSn] + tv.z;
    ov.w = er[(r+3) % TAGSn] + tv.w;
    o4[r4] = ov;
  }
}

// int tail outputs as floats
__global__ void k_tail(const int* __restrict__ tm, const int* __restrict__ ln,
                       const int* __restrict__ tc, float* __restrict__ out){
  const int i = blockIdx.x*256 + threadIdx.x;
  if (i < 8192)       out[i] = (float)tm[i];
  else if (i < 8256)  out[i] = (float)ln[i-8192];
  else if (i < 16448) out[i] = (float)tc[i-8256];
}

// ---------------------------------------------------------------------------
extern "C" void kernel_launch(void* const* d_in, const int* in_sizes, int n_in,
                              void* d_out, int out_size, void* d_ws, size_t ws_size,
                              hipStream_t stream){
  (void)in_sizes; (void)n_in; (void)out_size; (void)ws_size;
  const int*   wmap   = (const int*)d_in[0];
  const int*   cmapsf = (const int*)d_in[1];
  const int*   cmapsb = (const int*)d_in[2];
  const float* cmakf  = (const float*)d_in[3];
  const float* cmakb  = (const float*)d_in[4];
  const int*   tmaps  = (const int*)d_in[5];
  const int*   tmapc  = (const int*)d_in[6];
  const int*   lengths= (const int*)d_in[7];
  const float* ceW    = (const float*)d_in[8];
  const float* fcWih  = (const float*)d_in[9];
  const float* fcWhh  = (const float*)d_in[10];
  const float* fcb    = (const float*)d_in[11];
  const float* bcWih  = (const float*)d_in[12];
  const float* bcWhh  = (const float*)d_in[13];
  const float* bcb    = (const float*)d_in[14];
  const float* weW    = (const float*)d_in[15];
  const float* wfWih  = (const float*)d_in[16];
  const float* wfWhh  = (const float*)d_in[17];
  const float* wfb    = (const float*)d_in[18];
  const float* wbWih  = (const float*)d_in[19];
  const float* wbWhh  = (const float*)d_in[20];
  const float* wbb    = (const float*)d_in[21];
  const float* hwWt   = (const float*)d_in[22];
  const float* hwbt   = (const float*)d_in[23];
  const float* hwWg   = (const float*)d_in[24];
  const float* hwbg   = (const float*)d_in[25];
  const float* emW    = (const float*)d_in[26];
  const float* emb    = (const float*)d_in[27];
  const float* trans  = (const float*)d_in[28];

  // workspace layout (float units)
  float* p = (float*)d_ws;
  size_t o = 0;
  float* CWf  = p + o; o += 100*1024;
  float* CWb  = p + o; o += 100*1024;
  unsigned short* W8cf = (unsigned short*)(p + o); o += 65536;   // 1024*256 B
  unsigned short* W8cb = (unsigned short*)(p + o); o += 65536;
  unsigned short* W8wf = (unsigned short*)(p + o); o += 65536;
  unsigned short* W8wb = (unsigned short*)(p + o); o += 65536;
  unsigned short* Wp16f = (unsigned short*)(p + o); o += 1024*DWPn/2;  // bf16 1024x640
  unsigned short* Wp16b = (unsigned short*)(p + o); o += 1024*DWPn/2;
  unsigned short* hw16t = (unsigned short*)(p + o); o += 512*512/2;
  unsigned short* hw16g = (unsigned short*)(p + o); o += 512*512/2;
  unsigned short* em16W = (unsigned short*)(p + o); o += 128*512/2;
  float* embp = p + o; o += 128;
  int*   posf = (int*)(p + o); o += 64*512;
  int*   posb = (int*)(p + o); o += 64*512;
  unsigned short* sub16 = (unsigned short*)(p + o); o += (size_t)8192*512/2;  // also hout16
  float* hwz  = p + o; o += (size_t)8192*1024;                  // also wXf
  unsigned short* wq16 = (unsigned short*)(p + o); o += (size_t)8192*DWPn/2; // also em
  float* wXb  = p + o; o += (size_t)8192*1024;
  float* wXf  = hwz;
  unsigned short* hout16 = sub16;
  float* em   = (float*)wq16;

  float* out  = (float*)d_out;

  hipMemsetAsync(sub16, 0, (size_t)8192*512*2, stream);

  k_prep_cw <<<dim3(100,2), 256, 0, stream>>>(ceW, fcWih, fcb, bcWih, bcb, CWf, CWb);
  k_prep_w8 <<<dim3(512,4), 256, 0, stream>>>(fcWhh, bcWhh, wfWhh, wbWhh,
                                              W8cf, W8cb, W8wf, W8wb);
  k_pad16   <<<dim3(1024,2), 256, 0, stream>>>(wfWih, wbWih, Wp16f, Wp16b);
  k_w16     <<<dim3(512,2), 256, 0, stream>>>(hwWt, hwWg, hw16t, hw16g);
  k_em16    <<<128, 256, 0, stream>>>(emW, emb, em16W, embp);
  k_prep_pos<<<dim3(64,2), 64, 0, stream>>>(cmakf, cmakb, posf, posb);

  k_char_lstm<<<32, 1024, 0, stream>>>(cmapsf, cmapsb, CWf, CWb,
                                       (const unsigned char*)W8cf, (const unsigned char*)W8cb,
                                       posf, posb, sub16);

  // fused highway (reads + rewrites sub16 in place)
  k_hwgemm<<<dim3(64,4), 256, 0, stream>>>(sub16, hw16t, hw16g, hwbt, hwbg);

  k_wasm16<<<8192, 256, 0, stream>>>(wmap, weW, sub16, wq16);

  // word input projections: wX_d = w @ Wih_d^T + b_d
  k_gemm16<<<dim3(64,8,2), 256, 0, stream>>>(wq16, DWPn, DWPn,
                                             Wp16f, Wp16b, DWPn,
                                             wfb, wbb,
                                             wXf, wXb, 1024);

  k_word_lstm<<<64, 1024, 0, stream>>>(wXf, wXb,
                                       (const unsigned char*)W8wf, (const unsigned char*)W8wb,
                                       hout16);

  // em = hout @ emW^T + emb (padded to 128 tags), ld 128
  k_gemm16<<<dim3(64,1,1), 256, 0, stream>>>(hout16, 512, 512,
                                             em16W, em16W, 512,
                                             embp, embp,
                                             em, em, 128);

  k_crf<<<8192, 256, 0, stream>>>(em, trans, out);
  k_tail<<<65, 256, 0, stream>>>(tmaps, lengths, tmapc, out + (size_t)20480000);
}

// Round 15
// 670.963 us; speedup vs baseline: 1.0375x; 1.0375x over previous
//
#include <hip/hip_runtime.h>
#include <math.h>

#define Bn 64
#define Tn 128
#define TCn 512
#define CEn 64
#define CHn 256
#define TAGSn 50
#define DWPn 640   // word-LSTM input dim padded 612 -> 640

typedef float f32x4 __attribute__((ext_vector_type(4)));
typedef int   i32x4 __attribute__((ext_vector_type(4)));
typedef short bf16x8 __attribute__((ext_vector_type(8)));

#define DEQ 3.07578740157480315e-5f   // 1/(256*127)

__device__ __forceinline__ float sigf(float x){ return 1.0f/(1.0f+expf(-x)); }

__device__ __forceinline__ float fsig(float x){
  return __builtin_amdgcn_rcpf(1.f + exp2f(-1.4426950408889634f*x));
}
__device__ __forceinline__ float ftanh(float x){
  return 1.f - 2.f*__builtin_amdgcn_rcpf(1.f + exp2f(2.885390081777927f*x));
}

// barrier that drains only LDS (keeps global loads/stores in flight)
__device__ __forceinline__ void bar_lds(){
  asm volatile("s_waitcnt lgkmcnt(0)\n\ts_barrier" ::: "memory");
}

// f32 <-> bf16 (RNE)
__device__ __forceinline__ unsigned short f2bf(float x){
  unsigned u = __float_as_uint(x);
  u += 0x7fffu + ((u>>16)&1u);
  return (unsigned short)(u>>16);
}
__device__ __forceinline__ float bf2f(unsigned short h){
  return __uint_as_float(((unsigned)h)<<16);
}

// ---------------------------------------------------------------------------
// CW[d][c][u*4+k] = b_d[k*256+u] + sum_e ceW[c][e]*Wih_d[k*256+u][e]
__global__ void k_prep_cw(const float* __restrict__ ceW,
                          const float* __restrict__ Wf, const float* __restrict__ bf,
                          const float* __restrict__ Wb, const float* __restrict__ bb,
                          float* __restrict__ CWf, float* __restrict__ CWb){
  const int c = blockIdx.x, u = threadIdx.x;
  const float* Wih  = blockIdx.y ? Wb : Wf;
  const float* bias = blockIdx.y ? bb : bf;
  float*       CW   = blockIdx.y ? CWb : CWf;
  __shared__ float ce[CEn];
  if (u < CEn) ce[u] = ceW[c*CEn + u];
  __syncthreads();
  float a[4];
  #pragma unroll
  for (int k=0;k<4;k++){
    const float* wr = Wih + (size_t)(k*CHn+u)*CEn;
    float s = bias[k*CHn+u];
    #pragma unroll 4
    for (int e=0;e<CEn;e++) s += ce[e]*wr[e];
    a[k]=s;
  }
  ((float4*)CW)[c*CHn+u] = make_float4(a[0],a[1],a[2],a[3]);
}

// i8 Whh, gate-tile row permutation:
//   out row rp = wv*64 + nt*16 + m  <-  src row nt*256 + wv*16 + m
__global__ void k_prep_w8(const float* __restrict__ W0, const float* __restrict__ W1,
                          const float* __restrict__ W2, const float* __restrict__ W3,
                          unsigned short* __restrict__ O0, unsigned short* __restrict__ O1,
                          unsigned short* __restrict__ O2, unsigned short* __restrict__ O3){
  const int w = blockIdx.y;
  const float* W = (w==0)?W0:(w==1)?W1:(w==2)?W2:W3;
  unsigned short* O = (w==0)?O0:(w==1)?O1:(w==2)?O2:O3;
  const int i = blockIdx.x*256 + threadIdx.x;      // 131072 pairs
  const int rp = i >> 7;
  const int kp = (i & 127) * 2;
  const int sr = (((rp>>4)&3)*256) + ((rp>>6)*16) + (rp&15);
  const int b0 = (int)rintf(fminf(fmaxf(W[(size_t)sr*CHn + kp  ]*256.f,-127.f),127.f));
  const int b1 = (int)rintf(fminf(fmaxf(W[(size_t)sr*CHn + kp+1]*256.f,-127.f),127.f));
  O[(size_t)rp*128 + (kp>>1)] = (unsigned short)((b0 & 0xff) | ((b1 & 0xff) << 8));
}

// pad word Wih (1024,612) -> bf16 (1024,640)
__global__ void k_pad16(const float* __restrict__ Wf, const float* __restrict__ Wb,
                        unsigned short* __restrict__ Pf, unsigned short* __restrict__ Pb){
  const int j = blockIdx.x;
  const float* Win        = blockIdx.y ? Wb : Wf;
  unsigned short* Wout    = blockIdx.y ? Pb : Pf;
  for (int col=threadIdx.x; col<DWPn; col+=256)
    Wout[(size_t)j*DWPn+col] = (col<612) ? f2bf(Win[(size_t)j*612+col]) : 0;
}

// hwWt/hwWg (512,512) -> bf16
__global__ void k_w16(const float* __restrict__ Wt, const float* __restrict__ Wg,
                      unsigned short* __restrict__ Ot, unsigned short* __restrict__ Og){
  const int j = blockIdx.x;
  const float* W       = blockIdx.y ? Wg : Wt;
  unsigned short* O    = blockIdx.y ? Og : Ot;
  for (int col=threadIdx.x; col<512; col+=256)
    O[(size_t)j*512+col] = f2bf(W[(size_t)j*512+col]);
}

// emW (50,512) -> bf16 (128,512) padded; emb -> fp32 (128) padded
__global__ void k_em16(const float* __restrict__ emW, const float* __restrict__ emb,
                       unsigned short* __restrict__ Wp, float* __restrict__ bp){
  const int j = blockIdx.x;
  for (int col=threadIdx.x; col<512; col+=256)
    Wp[(size_t)j*512+col] = (j<TAGSn) ? f2bf(emW[(size_t)j*512+col]) : 0;
  if (threadIdx.x==0) bp[j] = (j<TAGSn) ? emb[j] : 0.f;
}

// stable-compaction ranks from cmakers only; grid (64,2), 64 threads (1 wave)
__global__ void k_prep_pos(const float* __restrict__ cmf, const float* __restrict__ cmb,
                           int* __restrict__ pf, int* __restrict__ pb){
  const float* cm = blockIdx.y ? cmb : cmf;
  int* pos        = blockIdx.y ? pb : pf;
  const int n = blockIdx.x, lane = threadIdx.x;
  int base = 0;
  for (int c=0;c<TCn/64;c++){
    int t = c*64 + lane;
    bool m = cm[n*TCn+t] != 0.f;
    unsigned long long bal = __ballot(m);
    int before = __popcll(bal & ((1ULL<<lane)-1ULL));
    int r = base + before;
    pos[n*TCn+t] = (m && r < Tn) ? r : -1;
    base += __popcll(bal);
  }
}

// ---------------------------------------------------------------------------
// char LSTM via i8 MFMA, gates in-register, 1 barrier/step, unroll-2,
// precomputed LDS addrs, DPP pack. 32 blocks, 1024 threads = 16 waves.
__global__ __launch_bounds__(1024, 4)
void k_char_lstm(const int* __restrict__ cmf, const int* __restrict__ cmb,
                 const float* __restrict__ CWf, const float* __restrict__ CWb,
                 const unsigned char* __restrict__ W8f, const unsigned char* __restrict__ W8b,
                 const int* __restrict__ posf, const int* __restrict__ posb,
                 unsigned short* __restrict__ sub16){
  const int dir = blockIdx.x >> 4, mg = blockIdx.x & 15;
  const int n0 = mg*4;
  const int t1 = threadIdx.x;
  const int wv = t1 >> 6, lane = t1 & 63;
  const int m = lane & 15, g = lane >> 4;
  const int*    cm  = dir ? cmb : cmf;
  const float4* CW  = (const float4*)(dir ? CWb : CWf);
  const unsigned char* W8 = dir ? W8b : W8f;
  const int*    pos = dir ? posb : posf;
  const int dofs = dir ? CHn : 0;

  __shared__ unsigned hbw[2][16][64];   // i8 h, 16B chunk idx XOR row; rows 4j = seq j

  i32x4 Bfr[4][4];
  #pragma unroll
  for (int nt=0;nt<4;nt++)
    #pragma unroll
    for (int kt=0;kt<4;kt++)
      Bfr[nt][kt] = *(const i32x4*)(W8 + (size_t)(wv*64 + nt*16 + m)*256 + kt*64 + g*16);

  for (int j=t1; j<2*16*64; j+=1024) ((unsigned*)hbw)[j] = 0u;
  const int uu = wv*16 + m;
  const int seq = n0 + g;
  const int* cmp  = cm  + seq*TCn;
  const int* posp = pos + seq*TCn;
  unsigned short* subp = sub16 + (size_t)seq*Tn*512 + dofs + uu;

  // precomputed LDS addresses (two parity sets)
  const int dwi = ((wv ^ (4*g)) << 2) | (m >> 2);
  unsigned* wp0 = &hbw[1][4*g][dwi];   // body par=0 writes buf 1
  unsigned* wp1 = &hbw[0][4*g][dwi];
  const i32x4* rp0[4]; const i32x4* rp1[4];
  {
    const char* r0 = (const char*)&hbw[0][0][0] + m*256;
    const char* r1 = (const char*)&hbw[1][0][0] + m*256;
    #pragma unroll
    for (int kt=0;kt<4;kt++){
      const int off = ((kt*4+g)^m)<<4;
      rp0[kt] = (const i32x4*)(r0 + off);
      rp1[kt] = (const i32x4*)(r1 + off);
    }
  }
  float cst = 0.f;
  __syncthreads();

  int    pp = posp[0];
  float4 cw = CW[(size_t)cmp[0]*CHn + uu];

#define CBODY(T, RP, WP) { \
    i32x4 a0 = *(RP)[0], a1 = *(RP)[1], a2 = *(RP)[2], a3 = *(RP)[3]; \
    const int tn_ = ((T)+1 < TCn) ? (T)+1 : (T); \
    const int ci2 = cmp[tn_]; \
    const int pp2 = posp[tn_]; \
    const float4 cw2 = CW[(size_t)ci2*CHn + uu]; \
    i32x4 c0={0,0,0,0}, c1={0,0,0,0}, c2={0,0,0,0}, c3={0,0,0,0}; \
    c0 = __builtin_amdgcn_mfma_i32_16x16x64_i8(a0, Bfr[0][0], c0, 0,0,0); \
    c1 = __builtin_amdgcn_mfma_i32_16x16x64_i8(a0, Bfr[1][0], c1, 0,0,0); \
    c2 = __builtin_amdgcn_mfma_i32_16x16x64_i8(a0, Bfr[2][0], c2, 0,0,0); \
    c3 = __builtin_amdgcn_mfma_i32_16x16x64_i8(a0, Bfr[3][0], c3, 0,0,0); \
    c0 = __builtin_amdgcn_mfma_i32_16x16x64_i8(a1, Bfr[0][1], c0, 0,0,0); \
    c1 = __builtin_amdgcn_mfma_i32_16x16x64_i8(a1, Bfr[1][1], c1, 0,0,0); \
    c2 = __builtin_amdgcn_mfma_i32_16x16x64_i8(a1, Bfr[2][1], c2, 0,0,0); \
    c3 = __builtin_amdgcn_mfma_i32_16x16x64_i8(a1, Bfr[3][1], c3, 0,0,0); \
    c0 = __builtin_amdgcn_mfma_i32_16x16x64_i8(a2, Bfr[0][2], c0, 0,0,0); \
    c1 = __builtin_amdgcn_mfma_i32_16x16x64_i8(a2, Bfr[1][2], c1, 0,0,0); \
    c2 = __builtin_amdgcn_mfma_i32_16x16x64_i8(a2, Bfr[2][2], c2, 0,0,0); \
    c3 = __builtin_amdgcn_mfma_i32_16x16x64_i8(a2, Bfr[3][2], c3, 0,0,0); \
    c0 = __builtin_amdgcn_mfma_i32_16x16x64_i8(a3, Bfr[0][3], c0, 0,0,0); \
    c1 = __builtin_amdgcn_mfma_i32_16x16x64_i8(a3, Bfr[1][3], c1, 0,0,0); \
    c2 = __builtin_amdgcn_mfma_i32_16x16x64_i8(a3, Bfr[2][3], c2, 0,0,0); \
    c3 = __builtin_amdgcn_mfma_i32_16x16x64_i8(a3, Bfr[3][3], c3, 0,0,0); \
    const float zi = fmaf((float)c0[0], DEQ, cw.x); \
    const float zf = fmaf((float)c1[0], DEQ, cw.y); \
    const float zg = fmaf((float)c2[0], DEQ, cw.z); \
    const float zo = fmaf((float)c3[0], DEQ, cw.w); \
    cst = fsig(zf)*cst + fsig(zi)*ftanh(zg); \
    const float hn = fsig(zo)*ftanh(cst); \
    int vv = ((int)rintf(hn*127.f)) & 0xff; \
    int tv = __builtin_amdgcn_mov_dpp(vv, 0xB1, 0xF, 0xF, true); \
    vv = (lane&1) ? ((vv<<8)|tv) : ((tv<<8)|vv); \
    tv = __builtin_amdgcn_mov_dpp(vv, 0x4E, 0xF, 0xF, true); \
    vv = (lane&2) ? ((vv<<16)|tv) : ((tv<<16)|vv); \
    if ((lane&3)==0) *(WP) = (unsigned)vv; \
    if (pp>=0) subp[(size_t)pp*512] = f2bf(hn); \
    bar_lds(); \
    pp = pp2; cw = cw2; }

  for (int t=0;t<TCn;t+=2){
    #pragma unroll
    for (int nt=0;nt<4;nt++)
      #pragma unroll
      for (int kt=0;kt<4;kt++)
        asm volatile("" : "+v"(Bfr[nt][kt]));
    CBODY(t,   rp0, wp0)
    CBODY(t+1, rp1, wp1)
  }
#undef CBODY
}

// ---------------------------------------------------------------------------
// word LSTM via i8 MFMA, same structure; writes bf16 hout. 64 blocks.
__global__ __launch_bounds__(1024, 4)
void k_word_lstm(const float* __restrict__ wXf, const float* __restrict__ wXb,
                 const unsigned char* __restrict__ W8f, const unsigned char* __restrict__ W8b,
                 unsigned short* __restrict__ hout16){
  const int dir = blockIdx.x >> 5, mg = blockIdx.x & 31;
  const int t0r = mg*4;
  const int t1 = threadIdx.x;
  const int wv = t1 >> 6, lane = t1 & 63;
  const int m = lane & 15, g = lane >> 4;
  const float* wX = dir ? wXb : wXf;
  const unsigned char* W8 = dir ? W8b : W8f;
  const int dofs = dir ? CHn : 0;

  __shared__ unsigned hbw[2][16][64];

  i32x4 Bfr[4][4];
  #pragma unroll
  for (int nt=0;nt<4;nt++)
    #pragma unroll
    for (int kt=0;kt<4;kt++)
      Bfr[nt][kt] = *(const i32x4*)(W8 + (size_t)(wv*64 + nt*16 + m)*256 + kt*64 + g*16);

  for (int j=t1; j<2*16*64; j+=1024) ((unsigned*)hbw)[j] = 0u;
  const int uu = wv*16 + m;
  const int row = t0r + g;
  const float* xbase = wX + (size_t)row*1024 + uu;
  unsigned short* hop = hout16 + (size_t)row*512 + dofs + uu;

  const int dwi = ((wv ^ (4*g)) << 2) | (m >> 2);
  unsigned* wp0 = &hbw[1][4*g][dwi];
  unsigned* wp1 = &hbw[0][4*g][dwi];
  const i32x4* rp0[4]; const i32x4* rp1[4];
  {
    const char* r0 = (const char*)&hbw[0][0][0] + m*256;
    const char* r1 = (const char*)&hbw[1][0][0] + m*256;
    #pragma unroll
    for (int kt=0;kt<4;kt++){
      const int off = ((kt*4+g)^m)<<4;
      rp0[kt] = (const i32x4*)(r0 + off);
      rp1[kt] = (const i32x4*)(r1 + off);
    }
  }
  float cst = 0.f;
  __syncthreads();

  {
    const int n00 = dir ? 63 : 0;
    const float* xp0 = xbase + (size_t)n00*131072;
    float4 zin = make_float4(xp0[0], xp0[256], xp0[512], xp0[768]);

#define WBODY(S, RP, WP) { \
    i32x4 a0 = *(RP)[0], a1 = *(RP)[1], a2 = *(RP)[2], a3 = *(RP)[3]; \
    const int n = dir ? (63-(S)) : (S); \
    const int sn_ = ((S)+1 < 64) ? (S)+1 : (S); \
    const int n2 = dir ? (63-sn_) : sn_; \
    const float* xp2 = xbase + (size_t)n2*131072; \
    const float4 zin2 = make_float4(xp2[0], xp2[256], xp2[512], xp2[768]); \
    i32x4 c0={0,0,0,0}, c1={0,0,0,0}, c2={0,0,0,0}, c3={0,0,0,0}; \
    c0 = __builtin_amdgcn_mfma_i32_16x16x64_i8(a0, Bfr[0][0], c0, 0,0,0); \
    c1 = __builtin_amdgcn_mfma_i32_16x16x64_i8(a0, Bfr[1][0], c1, 0,0,0); \
    c2 = __builtin_amdgcn_mfma_i32_16x16x64_i8(a0, Bfr[2][0], c2, 0,0,0); \
    c3 = __builtin_amdgcn_mfma_i32_16x16x64_i8(a0, Bfr[3][0], c3, 0,0,0); \
    c0 = __builtin_amdgcn_mfma_i32_16x16x64_i8(a1, Bfr[0][1], c0, 0,0,0); \
    c1 = __builtin_amdgcn_mfma_i32_16x16x64_i8(a1, Bfr[1][1], c1, 0,0,0); \
    c2 = __builtin_amdgcn_mfma_i32_16x16x64_i8(a1, Bfr[2][1], c2, 0,0,0); \
    c3 = __builtin_amdgcn_mfma_i32_16x16x64_i8(a1, Bfr[3][1], c3, 0,0,0); \
    c0 = __builtin_amdgcn_mfma_i32_16x16x64_i8(a2, Bfr[0][2], c0, 0,0,0); \
    c1 = __builtin_amdgcn_mfma_i32_16x16x64_i8(a2, Bfr[1][2], c1, 0,0,0); \
    c2 = __builtin_amdgcn_mfma_i32_16x16x64_i8(a2, Bfr[2][2], c2, 0,0,0); \
    c3 = __builtin_amdgcn_mfma_i32_16x16x64_i8(a2, Bfr[3][2], c3, 0,0,0); \
    c0 = __builtin_amdgcn_mfma_i32_16x16x64_i8(a3, Bfr[0][3], c0, 0,0,0); \
    c1 = __builtin_amdgcn_mfma_i32_16x16x64_i8(a3, Bfr[1][3], c1, 0,0,0); \
    c2 = __builtin_amdgcn_mfma_i32_16x16x64_i8(a3, Bfr[2][3], c2, 0,0,0); \
    c3 = __builtin_amdgcn_mfma_i32_16x16x64_i8(a3, Bfr[3][3], c3, 0,0,0); \
    const float zi = fmaf((float)c0[0], DEQ, zin.x); \
    const float zf = fmaf((float)c1[0], DEQ, zin.y); \
    const float zg = fmaf((float)c2[0], DEQ, zin.z); \
    const float zo = fmaf((float)c3[0], DEQ, zin.w); \
    cst = fsig(zf)*cst + fsig(zi)*ftanh(zg); \
    const float hn = fsig(zo)*ftanh(cst); \
    int vv = ((int)rintf(hn*127.f)) & 0xff; \
    int tv = __builtin_amdgcn_mov_dpp(vv, 0xB1, 0xF, 0xF, true); \
    vv = (lane&1) ? ((vv<<8)|tv) : ((tv<<8)|vv); \
    tv = __builtin_amdgcn_mov_dpp(vv, 0x4E, 0xF, 0xF, true); \
    vv = (lane&2) ? ((vv<<16)|tv) : ((tv<<16)|vv); \
    if ((lane&3)==0) *(WP) = (unsigned)vv; \
    hop[(size_t)n*65536] = f2bf(hn); \
    bar_lds(); \
    zin = zin2; }

    for (int s=0;s<64;s+=2){
      #pragma unroll
      for (int nt=0;nt<4;nt++)
        #pragma unroll
        for (int kt=0;kt<4;kt++)
          asm volatile("" : "+v"(Bfr[nt][kt]));
      WBODY(s,   rp0, wp0)
      WBODY(s+1, rp1, wp1)
    }
#undef WBODY
  }
}

// ---------------------------------------------------------------------------
// bf16 MFMA GEMM with register-staged double-buffer:
// C[m][n] = bias[n] + sum_k A[m][k]*W[n][k]; 128x128 tile, 256 thr, BK=32.
__global__ __launch_bounds__(256)
void k_gemm16(const unsigned short* __restrict__ A, int lda, int K,
              const unsigned short* __restrict__ W0, const unsigned short* __restrict__ W1, int ldw,
              const float* __restrict__ b0, const float* __restrict__ b1,
              float* __restrict__ C0, float* __restrict__ C1, int ldc){
  const unsigned short* W = blockIdx.z ? W1 : W0;
  const float* bias       = blockIdx.z ? b1 : b0;
  float*       C          = blockIdx.z ? C1 : C0;
  const int m0 = blockIdx.x*128, n0 = blockIdx.y*128;
  const int tid = threadIdx.x;
  const int wid = tid >> 6, l = tid & 63;
  const int wr = wid >> 1, wc = wid & 1;
  const int lm = l & 15, lk = l >> 4;
  __shared__ unsigned short As[128][40];
  __shared__ unsigned short Bs[128][40];
  f32x4 acc[4][4];
  #pragma unroll
  for (int i=0;i<4;i++)
    #pragma unroll
    for (int j=0;j<4;j++){ acc[i][j][0]=0.f; acc[i][j][1]=0.f; acc[i][j][2]=0.f; acc[i][j][3]=0.f; }

  const int sr = tid >> 1, sh = (tid & 1) * 16;
  const unsigned short* Ap = A + (size_t)(m0+sr)*lda + sh;
  const unsigned short* Wp = W + (size_t)(n0+sr)*ldw + sh;
  uint4 ra0 = *(const uint4*)(Ap);
  uint4 ra1 = *(const uint4*)(Ap + 8);
  uint4 rb0 = *(const uint4*)(Wp);
  uint4 rb1 = *(const uint4*)(Wp + 8);

  for (int kc=0; kc<K; kc+=32){
    *(uint4*)&As[sr][sh]   = ra0;
    *(uint4*)&As[sr][sh+8] = ra1;
    *(uint4*)&Bs[sr][sh]   = rb0;
    *(uint4*)&Bs[sr][sh+8] = rb1;
    __syncthreads();
    if (kc + 32 < K){               // prefetch next chunk under the MFMAs
      ra0 = *(const uint4*)(Ap + kc + 32);
      ra1 = *(const uint4*)(Ap + kc + 40);
      rb0 = *(const uint4*)(Wp + kc + 32);
      rb1 = *(const uint4*)(Wp + kc + 40);
    }
    bf16x8 af[4], bfr[4];
    #pragma unroll
    for (int mt=0;mt<4;mt++) af[mt]  = *(const bf16x8*)&As[wr*64+mt*16+lm][lk*8];
    #pragma unroll
    for (int nt=0;nt<4;nt++) bfr[nt] = *(const bf16x8*)&Bs[wc*64+nt*16+lm][lk*8];
    #pragma unroll
    for (int mt=0;mt<4;mt++)
      #pragma unroll
      for (int nt=0;nt<4;nt++)
        acc[mt][nt] = __builtin_amdgcn_mfma_f32_16x16x32_bf16(af[mt], bfr[nt], acc[mt][nt], 0,0,0);
    __syncthreads();
  }
  #pragma unroll
  for (int nt=0;nt<4;nt++){
    const int col = n0 + wc*64 + nt*16 + lm;
    const float bv = bias[col];
    #pragma unroll
    for (int mt=0;mt<4;mt++){
      const int r0 = m0 + wr*64 + mt*16 + lk*4;
      #pragma unroll
      for (int rg=0;rg<4;rg++)
        C[(size_t)(r0+rg)*ldc + col] = acc[mt][nt][rg] + bv;
    }
  }
}

// ---------------------------------------------------------------------------
// fused highway: zt = sub@Wt^T+bt, zg = sub@Wg^T+bg computed together,
// epilogue writes sub16 = sig(zg)*relu(zt) + (1-sig(zg))*sub16.
// grid (64,4), 256 threads, K=512.
__global__ __launch_bounds__(256, 1)
void k_hwgemm(unsigned short* __restrict__ sub16,
              const unsigned short* __restrict__ Wt, const unsigned short* __restrict__ Wg,
              const float* __restrict__ bt, const float* __restrict__ bg){
  const int m0 = blockIdx.x*128, n0 = blockIdx.y*128;
  const int tid = threadIdx.x;
  const int wid = tid >> 6, l = tid & 63;
  const int wr = wid >> 1, wc = wid & 1;
  const int lm = l & 15, lk = l >> 4;
  __shared__ unsigned short As[128][40];
  __shared__ unsigned short Bt[128][40];
  __shared__ unsigned short Bg[128][40];
  f32x4 zt[4][4], zg[4][4];
  #pragma unroll
  for (int i=0;i<4;i++)
    #pragma unroll
    for (int j=0;j<4;j++){
      zt[i][j][0]=0.f; zt[i][j][1]=0.f; zt[i][j][2]=0.f; zt[i][j][3]=0.f;
      zg[i][j][0]=0.f; zg[i][j][1]=0.f; zg[i][j][2]=0.f; zg[i][j][3]=0.f;
    }

  const int sr = tid >> 1, sh = (tid & 1) * 16;
  const unsigned short* Ap = sub16 + (size_t)(m0+sr)*512 + sh;
  const unsigned short* Tp = Wt + (size_t)(n0+sr)*512 + sh;
  const unsigned short* Gp = Wg + (size_t)(n0+sr)*512 + sh;
  uint4 ra0 = *(const uint4*)(Ap);
  uint4 ra1 = *(const uint4*)(Ap + 8);
  uint4 rt0 = *(const uint4*)(Tp);
  uint4 rt1 = *(const uint4*)(Tp + 8);
  uint4 rg0 = *(const uint4*)(Gp);
  uint4 rg1 = *(const uint4*)(Gp + 8);

  for (int kc=0; kc<512; kc+=32){
    *(uint4*)&As[sr][sh]   = ra0;
    *(uint4*)&As[sr][sh+8] = ra1;
    *(uint4*)&Bt[sr][sh]   = rt0;
    *(uint4*)&Bt[sr][sh+8] = rt1;
    *(uint4*)&Bg[sr][sh]   = rg0;
    *(uint4*)&Bg[sr][sh+8] = rg1;
    __syncthreads();
    if (kc + 32 < 512){
      ra0 = *(const uint4*)(Ap + kc + 32);
      ra1 = *(const uint4*)(Ap + kc + 40);
      rt0 = *(const uint4*)(Tp + kc + 32);
      rt1 = *(const uint4*)(Tp + kc + 40);
      rg0 = *(const uint4*)(Gp + kc + 32);
      rg1 = *(const uint4*)(Gp + kc + 40);
    }
    bf16x8 af[4], bt_[4], bg_[4];
    #pragma unroll
    for (int mt=0;mt<4;mt++) af[mt]  = *(const bf16x8*)&As[wr*64+mt*16+lm][lk*8];
    #pragma unroll
    for (int nt=0;nt<4;nt++){
      bt_[nt] = *(const bf16x8*)&Bt[wc*64+nt*16+lm][lk*8];
      bg_[nt] = *(const bf16x8*)&Bg[wc*64+nt*16+lm][lk*8];
    }
    #pragma unroll
    for (int mt=0;mt<4;mt++)
      #pragma unroll
      for (int nt=0;nt<4;nt++){
        zt[mt][nt] = __builtin_amdgcn_mfma_f32_16x16x32_bf16(af[mt], bt_[nt], zt[mt][nt], 0,0,0);
        zg[mt][nt] = __builtin_amdgcn_mfma_f32_16x16x32_bf16(af[mt], bg_[nt], zg[mt][nt], 0,0,0);
      }
    __syncthreads();
  }
  #pragma unroll
  for (int nt=0;nt<4;nt++){
    const int col = n0 + wc*64 + nt*16 + lm;
    const float btv = bt[col], bgv = bg[col];
    #pragma unroll
    for (int mt=0;mt<4;mt++){
      const int r0 = m0 + wr*64 + mt*16 + lk*4;
      #pragma unroll
      for (int rg=0;rg<4;rg++){
        const int row = r0 + rg;
        unsigned short* sp = sub16 + (size_t)row*512 + col;
        const float zt_v = zt[mt][nt][rg] + btv;
        const float zg_v = zg[mt][nt][rg] + bgv;
        const float gg = sigf(zg_v);
        const float tr = fmaxf(zt_v, 0.f);
        *sp = f2bf(gg*tr + (1.f-gg)*bf2f(*sp));
      }
    }
  }
}

// assemble padded word input (bf16)
__global__ void k_wasm16(const int* __restrict__ wmap, const float* __restrict__ weW,
                         const unsigned short* __restrict__ sub16,
                         unsigned short* __restrict__ wq16){
  const int m = blockIdx.x;
  const int wi = wmap[m];
  for (int col=threadIdx.x; col<DWPn; col+=256){
    unsigned short v = 0;
    if (col < 100)      v = f2bf(weW[(size_t)wi*100 + col]);
    else if (col < 612) v = sub16[(size_t)m*512 + (col-100)];
    wq16[(size_t)m*DWPn + col] = v;
  }
}

// crf[m][a][b] = em[m][b] + trans[a][b] ; em ld=128 ; float4 writes
__global__ __launch_bounds__(256)
void k_crf(const float* __restrict__ em, const float* __restrict__ trans,
           float* __restrict__ out){
  const int m = blockIdx.x;
  __shared__ float er[TAGSn];
  if (threadIdx.x < TAGSn) er[threadIdx.x] = em[(size_t)m*128 + threadIdx.x];
  __syncthreads();
  float4* o4 = (float4*)(out + (size_t)m*2500);
  const float4* t4 = (const float4*)trans;
  for (int r4=threadIdx.x; r4<625; r4+=256){
    const float4 tv = t4[r4];
    const int r = r4*4;
    float4 ov;
    ov.x = er[(r  ) % TAGSn] + tv.x;
    ov.y = er[(r+1) % TAGSn] + tv.y;
    ov.z = er[(r+2) % TAGSn] + tv.z;
    ov.w = er[(r+3) % TAGSn] + tv.w;
    o4[r4] = ov;
  }
}

// int tail outputs as floats
__global__ void k_tail(const int* __restrict__ tm, const int* __restrict__ ln,
                       const int* __restrict__ tc, float* __restrict__ out){
  const int i = blockIdx.x*256 + threadIdx.x;
  if (i < 8192)       out[i] = (float)tm[i];
  else if (i < 8256)  out[i] = (float)ln[i-8192];
  else if (i < 16448) out[i] = (float)tc[i-8256];
}

// ---------------------------------------------------------------------------
extern "C" void kernel_launch(void* const* d_in, const int* in_sizes, int n_in,
                              void* d_out, int out_size, void* d_ws, size_t ws_size,
                              hipStream_t stream){
  (void)in_sizes; (void)n_in; (void)out_size; (void)ws_size;
  const int*   wmap   = (const int*)d_in[0];
  const int*   cmapsf = (const int*)d_in[1];
  const int*   cmapsb = (const int*)d_in[2];
  const float* cmakf  = (const float*)d_in[3];
  const float* cmakb  = (const float*)d_in[4];
  const int*   tmaps  = (const int*)d_in[5];
  const int*   tmapc  = (const int*)d_in[6];
  const int*   lengths= (const int*)d_in[7];
  const float* ceW    = (const float*)d_in[8];
  const float* fcWih  = (const float*)d_in[9];
  const float* fcWhh  = (const float*)d_in[10];
  const float* fcb    = (const float*)d_in[11];
  const float* bcWih  = (const float*)d_in[12];
  const float* bcWhh  = (const float*)d_in[13];
  const float* bcb    = (const float*)d_in[14];
  const float* weW    = (const float*)d_in[15];
  const float* wfWih  = (const float*)d_in[16];
  const float* wfWhh  = (const float*)d_in[17];
  const float* wfb    = (const float*)d_in[18];
  const float* wbWih  = (const float*)d_in[19];
  const float* wbWhh  = (const float*)d_in[20];
  const float* wbb    = (const float*)d_in[21];
  const float* hwWt   = (const float*)d_in[22];
  const float* hwbt   = (const float*)d_in[23];
  const float* hwWg   = (const float*)d_in[24];
  const float* hwbg   = (const float*)d_in[25];
  const float* emW    = (const float*)d_in[26];
  const float* emb    = (const float*)d_in[27];
  const float* trans  = (const float*)d_in[28];

  // workspace layout (float units)
  float* p = (float*)d_ws;
  size_t o = 0;
  float* CWf  = p + o; o += 100*1024;
  float* CWb  = p + o; o += 100*1024;
  unsigned short* W8cf = (unsigned short*)(p + o); o += 65536;   // 1024*256 B
  unsigned short* W8cb = (unsigned short*)(p + o); o += 65536;
  unsigned short* W8wf = (unsigned short*)(p + o); o += 65536;
  unsigned short* W8wb = (unsigned short*)(p + o); o += 65536;
  unsigned short* Wp16f = (unsigned short*)(p + o); o += 1024*DWPn/2;  // bf16 1024x640
  unsigned short* Wp16b = (unsigned short*)(p + o); o += 1024*DWPn/2;
  unsigned short* hw16t = (unsigned short*)(p + o); o += 512*512/2;
  unsigned short* hw16g = (unsigned short*)(p + o); o += 512*512/2;
  unsigned short* em16W = (unsigned short*)(p + o); o += 128*512/2;
  float* embp = p + o; o += 128;
  int*   posf = (int*)(p + o); o += 64*512;
  int*   posb = (int*)(p + o); o += 64*512;
  unsigned short* sub16 = (unsigned short*)(p + o); o += (size_t)8192*512/2;  // also hout16
  float* hwz  = p + o; o += (size_t)8192*1024;                  // also wXf
  unsigned short* wq16 = (unsigned short*)(p + o); o += (size_t)8192*DWPn/2; // also em
  float* wXb  = p + o; o += (size_t)8192*1024;
  float* wXf  = hwz;
  unsigned short* hout16 = sub16;
  float* em   = (float*)wq16;

  float* out  = (float*)d_out;

  hipMemsetAsync(sub16, 0, (size_t)8192*512*2, stream);

  k_prep_cw <<<dim3(100,2), 256, 0, stream>>>(ceW, fcWih, fcb, bcWih, bcb, CWf, CWb);
  k_prep_w8 <<<dim3(512,4), 256, 0, stream>>>(fcWhh, bcWhh, wfWhh, wbWhh,
                                              W8cf, W8cb, W8wf, W8wb);
  k_pad16   <<<dim3(1024,2), 256, 0, stream>>>(wfWih, wbWih, Wp16f, Wp16b);
  k_w16     <<<dim3(512,2), 256, 0, stream>>>(hwWt, hwWg, hw16t, hw16g);
  k_em16    <<<128, 256, 0, stream>>>(emW, emb, em16W, embp);
  k_prep_pos<<<dim3(64,2), 64, 0, stream>>>(cmakf, cmakb, posf, posb);

  k_char_lstm<<<32, 1024, 0, stream>>>(cmapsf, cmapsb, CWf, CWb,
                                       (const unsigned char*)W8cf, (const unsigned char*)W8cb,
                                       posf, posb, sub16);

  // fused highway (reads + rewrites sub16 in place)
  k_hwgemm<<<dim3(64,4), 256, 0, stream>>>(sub16, hw16t, hw16g, hwbt, hwbg);

  k_wasm16<<<8192, 256, 0, stream>>>(wmap, weW, sub16, wq16);

  // word input projections: wX_d = w @ Wih_d^T + b_d
  k_gemm16<<<dim3(64,8,2), 256, 0, stream>>>(wq16, DWPn, DWPn,
                                             Wp16f, Wp16b, DWPn,
                                             wfb, wbb,
                                             wXf, wXb, 1024);

  k_word_lstm<<<64, 1024, 0, stream>>>(wXf, wXb,
                                       (const unsigned char*)W8wf, (const unsigned char*)W8wb,
                                       hout16);

  // em = hout @ emW^T + emb (padded to 128 tags), ld 128
  k_gemm16<<<dim3(64,1,1), 256, 0, stream>>>(hout16, 512, 512,
                                             em16W, em16W, 512,
                                             embp, embp,
                                             em, em, 128);

  k_crf<<<8192, 256, 0, stream>>>(em, trans, out);
  k_tail<<<65, 256, 0, stream>>>(tmaps, lengths, tmapc, out + (size_t)20480000);
}